// Round 12
// baseline (210.904 us; speedup 1.0000x reference)
//
#include <hip/hip_runtime.h>
#include <math.h>

// Problem constants (B, NP, NQ, D) = (4, 256, 256, 512)
#define BB   4
#define NP   256
#define NQ   256
#define DD   512
#define DD4  (DD / 4)

#define NSTORE       1792                  // store blocks (grid-stride)
#define TOTAL_CHUNKS 131072                // (B*NQ*NP*DD4)/256 4KB slabs

typedef float f32x4 __attribute__((ext_vector_type(4)));

static constexpr float kScale = 1.0f / 22.627417f;  // 1/sqrt(512)

// ---------------------------------------------------------------------------
// Launch 1: gate table. 4 softmax rows per block of q_scores = qq.qk^T / T,
// written to ws[b][n][p] (1 MB). Grid (64, 4).
// ---------------------------------------------------------------------------
__global__ __launch_bounds__(256) void gate_kernel(
    const float* __restrict__ qq,    // [B, NQ, D]
    const float* __restrict__ qk,    // [B, NP, D]
    float* __restrict__ gws)         // [B, NQ, NP]
{
    const int b  = blockIdx.y;
    const int n0 = blockIdx.x * 4;
    const int t  = threadIdx.x;

    const f32x4* krow = (const f32x4*)(qk + ((size_t)b * NP + t) * DD);
    const float* qb   = qq + ((size_t)b * NQ + n0) * DD;   // wave-uniform

    float acc[4] = {0.f, 0.f, 0.f, 0.f};
    #pragma unroll 8
    for (int d4 = 0; d4 < DD4; ++d4) {
        const f32x4 kv = krow[d4];
        #pragma unroll
        for (int r = 0; r < 4; ++r) {
            const float* qr = qb + r * DD + d4 * 4;
            acc[r] += qr[0] * kv.x + qr[1] * kv.y + qr[2] * kv.z + qr[3] * kv.w;
        }
    }

    __shared__ __align__(16) float ss[4][256];
    #pragma unroll
    for (int r = 0; r < 4; ++r) ss[r][t] = acc[r] * kScale;
    __syncthreads();

    const int r = t >> 6;
    const int g = t & 63;
    const f32x4 sv = ((const f32x4*)ss[r])[g];

    float m = fmaxf(fmaxf(sv.x, sv.y), fmaxf(sv.z, sv.w));
    #pragma unroll
    for (int off = 32; off >= 1; off >>= 1) m = fmaxf(m, __shfl_xor(m, off, 64));

    f32x4 ev;
    ev.x = expf(sv.x - m); ev.y = expf(sv.y - m);
    ev.z = expf(sv.z - m); ev.w = expf(sv.w - m);
    float s = (ev.x + ev.y) + (ev.z + ev.w);
    #pragma unroll
    for (int off = 32; off >= 1; off >>= 1) s += __shfl_xor(s, off, 64);

    ((f32x4*)(gws + ((size_t)b * NQ + n0 + r) * NP))[g] = ev * (1.0f / s);
}

// ---------------------------------------------------------------------------
// Launch 2, grid.x = NSTORE + 256 — R9 verbatim with ONE change: PLAIN
// stores instead of nontemporal. Sweeping order (active write window = one
// contiguous ~7MB region) should let L2 evict dirty lines in address order,
// matching the 6.8 TB/s rocclr-fill pattern. A/B vs R9's NT = 134.7us.
// ---------------------------------------------------------------------------
__global__ __launch_bounds__(256) void store_kernel(
    const float* __restrict__ q,     // [B, NP, D]
    const float* __restrict__ k,     // [B, NP, D]
    const f32x4* __restrict__ v4,    // [B, NP, DD4]
    const f32x4* __restrict__ qv4,   // [B, NQ, DD4]
    const float* __restrict__ gws,   // [B, NQ, NP]
    f32x4* __restrict__ out4,        // [B, NQ, NP, DD4]
    float* __restrict__ attn_out,    // [B, NP, NP]
    float* __restrict__ logattn_out) // [B, NP, NP]
{
    const int t = threadIdx.x;

    if (blockIdx.x < (unsigned)NSTORE) {
        const int h  = t >> 7;            // 0/1: which p of the slab
        const int d4 = t & (DD4 - 1);

        for (int c = blockIdx.x; c < TOTAL_CHUNKS; c += NSTORE) {
            const int b = c >> 15;
            const int n = (c >> 7) & 255;
            const int p = (2 * c + h) & 255;

            int gidx = (((b << 8) + n) << 8) + p;
            gidx = __builtin_amdgcn_readfirstlane(gidx);   // force s_load
            const float gpn = gws[gidx];

            const f32x4 vv  = v4[(((size_t)(b << 8) + p) << 7) + d4];
            const f32x4 qvv = qv4[(((size_t)(b << 8) + n) << 7) + d4];
            out4[((size_t)c << 8) + t] = (vv + qvv) * gpn;  // PLAIN store (A/B)
        }
    } else {
        // ---------------- type B: attn / log_attn softmax ----------------
        const int idx = blockIdx.x - NSTORE;   // 0..255
        const int b   = idx >> 6;
        const int p0  = (idx & 63) * 4;

        const f32x4* krow = (const f32x4*)(k + ((size_t)b * NP + t) * DD);
        const float* qb   = q + ((size_t)b * NP + p0) * DD;   // wave-uniform

        float acc[4] = {0.f, 0.f, 0.f, 0.f};
        #pragma unroll 8
        for (int d4 = 0; d4 < DD4; ++d4) {
            const f32x4 kv = krow[d4];
            #pragma unroll
            for (int r = 0; r < 4; ++r) {
                const float* qr = qb + r * DD + d4 * 4;
                acc[r] += qr[0] * kv.x + qr[1] * kv.y + qr[2] * kv.z + qr[3] * kv.w;
            }
        }

        __shared__ __align__(16) float ss[4][256];
        #pragma unroll
        for (int r = 0; r < 4; ++r) ss[r][t] = acc[r] * kScale;
        __syncthreads();

        const int r = t >> 6;
        const int g = t & 63;
        const f32x4 sv = ((const f32x4*)ss[r])[g];

        float m = fmaxf(fmaxf(sv.x, sv.y), fmaxf(sv.z, sv.w));
        #pragma unroll
        for (int off = 32; off >= 1; off >>= 1)
            m = fmaxf(m, __shfl_xor(m, off, 64));

        f32x4 ev;
        ev.x = expf(sv.x - m); ev.y = expf(sv.y - m);
        ev.z = expf(sv.z - m); ev.w = expf(sv.w - m);
        float s = (ev.x + ev.y) + (ev.z + ev.w);
        #pragma unroll
        for (int off = 32; off >= 1; off >>= 1) s += __shfl_xor(s, off, 64);

        const float inv = 1.0f / s;
        const float lse = logf(s);

        const size_t base = ((size_t)b * NP + (p0 + r)) * 256;
        ((f32x4*)(attn_out + base))[g] = ev * inv;
        f32x4 lg;
        lg.x = (sv.x - m) - lse; lg.y = (sv.y - m) - lse;
        lg.z = (sv.z - m) - lse; lg.w = (sv.w - m) - lse;
        ((f32x4*)(logattn_out + base))[g] = lg;
    }
}

extern "C" void kernel_launch(void* const* d_in, const int* in_sizes, int n_in,
                              void* d_out, int out_size, void* d_ws, size_t ws_size,
                              hipStream_t stream) {
    // setup_inputs order: q, k, v, query(unused), query_q, query_k, query_v
    const float* q  = (const float*)d_in[0];
    const float* k  = (const float*)d_in[1];
    const float* v  = (const float*)d_in[2];
    const float* qq = (const float*)d_in[4];
    const float* qk = (const float*)d_in[5];
    const float* qv = (const float*)d_in[6];

    float* out = (float*)d_out;
    const size_t out_elems = (size_t)BB * NQ * NP * DD;          // 134,217,728
    float* attn_out    = out + out_elems;                         // [B,NP,256]
    float* logattn_out = attn_out + (size_t)BB * NP * 256;        // [B,NP,256]

    float* gws = (float*)d_ws;       // 4*256*256*4 = 1 MB of scratch

    // 1) gate table -> workspace.
    gate_kernel<<<dim3(NQ / 4, BB), 256, 0, stream>>>(qq, qk, gws);

    // 2) sweeping gated-combine PLAIN write + (hidden) attn/log_attn softmax.
    store_kernel<<<NSTORE + 256, 256, 0, stream>>>(
        q, k, (const f32x4*)v, (const f32x4*)qv, gws,
        (f32x4*)out, attn_out, logattn_out);
}